// Round 7
// baseline (1786.034 us; speedup 1.0000x reference)
//
#include <hip/hip_runtime.h>
#include <math.h>

#define B_ 8
#define N_ 2048
#define C_ 256
#define TOK (B_*N_)
#define T_ 64
#define NCH (N_/T_)   // 32 chunks per batch

struct GArgs {
  const float* W[6];
  const float* bias[6];
  float* outQ; float* outK; float* outV; float* outA; float* outB; float* outO;
};

// ---------------- DPP cross-lane reduction helpers (all-VALU, no DS) -------
template<int CTRL>
__device__ __forceinline__ float dpp_add(float x) {
  int r = __builtin_amdgcn_update_dpp(0, __float_as_int(x), CTRL, 0xF, 0xF, true);
  return x + __int_as_float(r);
}
__device__ __forceinline__ float red16(float x) {
  x = dpp_add<0xB1>(x);   // quad_perm xor1
  x = dpp_add<0x4E>(x);   // quad_perm xor2
  x = dpp_add<0x140>(x);  // row_mirror
  x = dpp_add<0x141>(x);  // row_half_mirror
  return x;
}
// Full 64-lane sum, valid in all lanes (via readlane 63).
__device__ __forceinline__ float red64(float x) {
  x = red16(x);
  x = dpp_add<0x142>(x);  // row_bcast15
  x = dpp_add<0x143>(x);  // row_bcast31
  return __int_as_float(__builtin_amdgcn_readlane(__float_as_int(x), 63));
}

__device__ __forceinline__ float dot4(const float4& a, const float4& b) {
  return (a.x*b.x + a.y*b.y) + (a.z*b.z + a.w*b.w);
}

// ---------------- Tiled f32 GEMM with fused epilogues (unchanged) ----------
__global__ __launch_bounds__(256) void gemm_multi(const float* __restrict__ X,
                                                  int pbase, GArgs ga) {
  const int p = pbase + blockIdx.y;
  const float* __restrict__ Wp = ga.W[p];
  const float* __restrict__ bp = ga.bias[p];
  const int rowBase = blockIdx.x * 64;
  const int tid = threadIdx.x;
  const int tx = tid & 15;
  const int ty = tid >> 4;

  __shared__ float xs[64][33];
  __shared__ float wsm[256][33];

  float acc[4][16];
  #pragma unroll
  for (int r = 0; r < 4; ++r)
    #pragma unroll
    for (int c = 0; c < 16; ++c) acc[r][c] = bp[tx + 16*c];

  for (int k0 = 0; k0 < C_; k0 += 32) {
    #pragma unroll
    for (int pass = 0; pass < 2; ++pass) {
      int flat = (pass*256 + tid) * 4;
      int r = flat >> 5, kk = flat & 31;
      const float4 v = *(const float4*)(X + (size_t)(rowBase + r)*C_ + k0 + kk);
      xs[r][kk] = v.x; xs[r][kk+1] = v.y; xs[r][kk+2] = v.z; xs[r][kk+3] = v.w;
    }
    #pragma unroll
    for (int pass = 0; pass < 8; ++pass) {
      int flat = (pass*256 + tid) * 4;
      int c = flat >> 5, kk = flat & 31;
      const float4 v = *(const float4*)(Wp + (size_t)c*C_ + k0 + kk);
      wsm[c][kk] = v.x; wsm[c][kk+1] = v.y; wsm[c][kk+2] = v.z; wsm[c][kk+3] = v.w;
    }
    __syncthreads();
    #pragma unroll
    for (int kk = 0; kk < 32; ++kk) {
      float xr[4];
      #pragma unroll
      for (int r = 0; r < 4; ++r) xr[r] = xs[ty*4 + r][kk];
      #pragma unroll
      for (int c = 0; c < 16; ++c) {
        float wv = wsm[tx + 16*c][kk];
        #pragma unroll
        for (int r = 0; r < 4; ++r) acc[r][c] += xr[r] * wv;
      }
    }
    __syncthreads();
  }

  if (p <= 2) {
    float part[4] = {0.f, 0.f, 0.f, 0.f};
    #pragma unroll
    for (int r = 0; r < 4; ++r)
      #pragma unroll
      for (int c = 0; c < 16; ++c) {
        float y = acc[r][c];
        float s = y / (1.f + __expf(-y));
        acc[r][c] = s;
        part[r] += s * s;
      }
    float* outp = (p == 0) ? ga.outQ : (p == 1) ? ga.outK : ga.outV;
    if (p == 2) {
      #pragma unroll
      for (int r = 0; r < 4; ++r)
        #pragma unroll
        for (int c = 0; c < 16; ++c)
          outp[(size_t)(rowBase + ty*4 + r)*C_ + tx + 16*c] = acc[r][c];
    } else {
      __syncthreads();
      float* red = &xs[0][0];
      float* rnorm = &wsm[0][0];
      #pragma unroll
      for (int r = 0; r < 4; ++r) red[(ty*4 + r)*17 + tx] = part[r];
      __syncthreads();
      if (tid < 64) {
        float s = 0.f;
        #pragma unroll
        for (int i = 0; i < 16; ++i) s += red[tid*17 + i];
        rnorm[tid] = 1.f / (sqrtf(s) + 1e-6f);
      }
      __syncthreads();
      #pragma unroll
      for (int r = 0; r < 4; ++r) {
        float sc = rnorm[ty*4 + r];
        #pragma unroll
        for (int c = 0; c < 16; ++c)
          outp[(size_t)(rowBase + ty*4 + r)*C_ + tx + 16*c] = acc[r][c] * sc;
      }
    }
  } else if (p <= 4) {
    float part[4] = {0.f, 0.f, 0.f, 0.f};
    #pragma unroll
    for (int r = 0; r < 4; ++r)
      #pragma unroll
      for (int c = 0; c < 16; ++c) {
        float y = acc[r][c];
        part[r] += 1.f / (1.f + __expf(-y));
      }
    __syncthreads();
    float* red = &xs[0][0];
    #pragma unroll
    for (int r = 0; r < 4; ++r) red[(ty*4 + r)*17 + tx] = part[r];
    __syncthreads();
    if (tid < 64) {
      float s = 0.f;
      #pragma unroll
      for (int i = 0; i < 16; ++i) s += red[tid*17 + i];
      ((p == 3) ? ga.outA : ga.outB)[rowBase + tid] = s * (1.f / 256.f);
    }
  } else {
    #pragma unroll
    for (int r = 0; r < 4; ++r)
      #pragma unroll
      for (int c = 0; c < 16; ++c)
        ga.outO[(size_t)(rowBase + ty*4 + r)*C_ + tx + 16*c] = acc[r][c];
  }
}

// ---------------- per-chunk Gram matrices: G = K K^T, QK = Q K^T -----------
// grid 256 = (b = bid&7, c = bid>>3); 256 threads.
__global__ __launch_bounds__(256) void gram_kernel(const float* __restrict__ kn,
                                                   const float* __restrict__ qn,
                                                   float* __restrict__ Gbuf,
                                                   float* __restrict__ QKbuf) {
  __shared__ float Kl[64][260];
  __shared__ float Ql[64][260];
  const int bid = blockIdx.x;
  const int b = bid & 7, c = bid >> 3;
  const size_t base = ((size_t)b*N_ + (size_t)c*T_) * C_;
  const int tid = threadIdx.x;
  #pragma unroll
  for (int p = 0; p < 16; ++p) {
    int flat = p*256 + tid;          // 4096 float4 slots
    int row = flat >> 6, c4 = flat & 63;
    *(float4*)&Kl[row][c4*4] = *(const float4*)(kn + base + (size_t)row*C_ + c4*4);
    *(float4*)&Ql[row][c4*4] = *(const float4*)(qn + base + (size_t)row*C_ + c4*4);
  }
  __syncthreads();
  const int trow = tid & 63, sg = tid >> 6;
  float accG[16], accQ[16];
  #pragma unroll
  for (int m = 0; m < 16; ++m) { accG[m] = 0.f; accQ[m] = 0.f; }
  for (int j4 = 0; j4 < 64; ++j4) {
    float4 kt = *(float4*)&Kl[trow][j4*4];
    float4 qt = *(float4*)&Ql[trow][j4*4];
    #pragma unroll
    for (int m = 0; m < 16; ++m) {
      float4 ks = *(float4*)&Kl[sg*16 + m][j4*4];   // same addr across 64 lanes: broadcast
      accG[m] += dot4(kt, ks);
      accQ[m] += dot4(qt, ks);
    }
  }
  float* Gp = Gbuf + (size_t)bid*4096;
  float* Qp = QKbuf + (size_t)bid*4096;
  #pragma unroll
  for (int m = 0; m < 16; ++m) {
    Gp[trow*64 + sg*16 + m] = accG[m];
    Qp[trow*64 + sg*16 + m] = accQ[m];
  }
}

// ---------------- per-chunk WY solves + intra output -----------------------
// grid 256 = (b,c); thread = column j (0..255). Computes:
//   gamma (cumprod a), U = (I+diag(b)G_sl)^-1 diag(b)K,
//   Qtilde = Q - tril(QK)U (in place over qn),
//   Y = (I+diag(b)Ghat_sl)^-1 diag(b)V,  Z = diag(gamT/gam)Y (in place over vO),
//   O_intra = Omega Y  -> d_out,  Omega[t][s] = tril(QK)[t][s]*gam[t]/gam[s].
__global__ __launch_bounds__(256) void solve_kernel(const float* __restrict__ kn,
                                                    float* __restrict__ qn,
                                                    float* __restrict__ vO,
                                                    const float* __restrict__ Ag,
                                                    const float* __restrict__ Bg,
                                                    const float* __restrict__ Gbuf,
                                                    const float* __restrict__ QKbuf,
                                                    float* __restrict__ Ubuf,
                                                    float* __restrict__ gbuf,
                                                    float* __restrict__ Oout) {
  __shared__ float Gl[64][68];
  __shared__ float Wl[64][68];
  __shared__ float gam[64], al[64], bl[64];
  const int bid = blockIdx.x;
  const int b = bid & 7, c = bid >> 3;
  const size_t ct0 = (size_t)b*N_ + (size_t)c*T_;
  const size_t base = ct0 * C_;
  const int j = threadIdx.x;

  #pragma unroll
  for (int p = 0; p < 16; ++p) {
    int idx = p*256 + j;
    int s = idx >> 6, r = idx & 63;
    float g  = Gbuf[(size_t)bid*4096 + idx];
    float qk = QKbuf[(size_t)bid*4096 + idx];
    Gl[s][r] = (r <  s) ? g  : 0.f;   // strict lower
    Wl[s][r] = (r <= s) ? qk : 0.f;   // lower incl diag
  }
  if (j < 64) { al[j] = Ag[ct0 + j]; bl[j] = Bg[ct0 + j]; }
  __syncthreads();
  if (j == 0) {
    float g = 1.f;
    for (int s = 0; s < 64; ++s) { g *= al[s]; gam[s] = g; }
  }
  __syncthreads();
  if (j < 64) gbuf[ct0 + j] = gam[j];

  // ---- U solve (masked-full inner: zeros kill r>=s terms) ----
  float u[64];
  #pragma unroll
  for (int s = 0; s < 64; ++s) u[s] = 0.f;
  #pragma unroll
  for (int s = 0; s < 64; ++s) {
    float4 av = make_float4(kn[base + (size_t)s*C_ + j], 0.f, 0.f, 0.f);
    float a0 = av.x, a1 = 0.f, a2 = 0.f, a3 = 0.f;
    #pragma unroll
    for (int r4 = 0; r4 < 16; ++r4) {
      float4 g = *(const float4*)&Gl[s][r4*4];
      a0 -= g.x * u[r4*4 + 0];
      a1 -= g.y * u[r4*4 + 1];
      a2 -= g.z * u[r4*4 + 2];
      a3 -= g.w * u[r4*4 + 3];
    }
    u[s] = bl[s] * ((a0 + a1) + (a2 + a3));
    Ubuf[base + (size_t)s*C_ + j] = u[s];
  }
  // ---- Qtilde (in place) ----
  #pragma unroll
  for (int t = 0; t < 64; ++t) {
    float a0 = qn[base + (size_t)t*C_ + j], a1 = 0.f, a2 = 0.f, a3 = 0.f;
    #pragma unroll
    for (int s4 = 0; s4 < 16; ++s4) {
      float4 w = *(const float4*)&Wl[t][s4*4];
      a0 -= w.x * u[s4*4 + 0];
      a1 -= w.y * u[s4*4 + 1];
      a2 -= w.z * u[s4*4 + 2];
      a3 -= w.w * u[s4*4 + 3];
    }
    qn[base + (size_t)t*C_ + j] = (a0 + a1) + (a2 + a3);
  }
  __syncthreads();
  // ---- scale: Gl -> Ghat, Wl -> Omega (row/col gamma ratios) ----
  #pragma unroll
  for (int p = 0; p < 16; ++p) {
    int idx = p*256 + j;
    int s = idx >> 6, r = idx & 63;
    float rs = gam[s] / gam[r];
    Gl[s][r] *= rs;
    Wl[s][r] *= rs;
  }
  __syncthreads();
  // ---- Y solve ----
  float y[64];
  #pragma unroll
  for (int s = 0; s < 64; ++s) y[s] = 0.f;
  #pragma unroll
  for (int s = 0; s < 64; ++s) {
    float a0 = vO[base + (size_t)s*C_ + j], a1 = 0.f, a2 = 0.f, a3 = 0.f;
    #pragma unroll
    for (int r4 = 0; r4 < 16; ++r4) {
      float4 g = *(const float4*)&Gl[s][r4*4];
      a0 -= g.x * y[r4*4 + 0];
      a1 -= g.y * y[r4*4 + 1];
      a2 -= g.z * y[r4*4 + 2];
      a3 -= g.w * y[r4*4 + 3];
    }
    y[s] = bl[s] * ((a0 + a1) + (a2 + a3));
  }
  const float gT = gam[63];
  #pragma unroll
  for (int s = 0; s < 64; ++s)
    vO[base + (size_t)s*C_ + j] = (gT / gam[s]) * y[s];   // Z
  // ---- O_intra = Omega * y ----
  #pragma unroll
  for (int t = 0; t < 64; ++t) {
    float a0 = 0.f, a1 = 0.f, a2 = 0.f, a3 = 0.f;
    #pragma unroll
    for (int s4 = 0; s4 < 16; ++s4) {
      float4 w = *(const float4*)&Wl[t][s4*4];
      a0 += w.x * y[s4*4 + 0];
      a1 += w.y * y[s4*4 + 1];
      a2 += w.z * y[s4*4 + 2];
      a3 += w.w * y[s4*4 + 3];
    }
    Oout[base + (size_t)t*C_ + j] = (a0 + a1) + (a2 + a3);
  }
}

// ---------------- serial chunk scan over S rows ---------------------------
// grid 512 = (b = bid&7, rb = bid>>3); rows i0 = rb*4; 4 waves = 1 row each.
// Lane l owns S[row][4l..4l+3]. Loops 32 chunks; per chunk:
//   PassA: o_cross[t] = gam[t]*(S . qtilde_t)  (+= into d_out via LDS)
//   PassBC: du_s = S . u_s (red64), coef = gamT*du_s - Z[s][row],
//           acc += coef*k_s;  S = gamT*S - acc.
// No inter-block communication (rows independent).
__global__ __launch_bounds__(256) void chunk_scan_kernel(const float* __restrict__ kn,
                                                         const float* __restrict__ qt,
                                                         const float* __restrict__ Ubuf,
                                                         const float* __restrict__ Zb,
                                                         const float* __restrict__ gbuf,
                                                         float* __restrict__ Oout) {
  __shared__ float Kl[64][260];
  __shared__ float Zl[64][4];
  __shared__ float gaml[64];
  __shared__ float Ol[64][4];
  const int bid = blockIdx.x;
  const int b = bid & 7, rb = bid >> 3;
  const int i0 = rb * 4;
  const int tid = threadIdx.x;
  const int w = tid >> 6, lane = tid & 63;

  float4 S = make_float4(0.f, 0.f, 0.f, 0.f);

  for (int cch = 0; cch < NCH; ++cch) {
    const size_t ct0 = (size_t)b*N_ + (size_t)cch*T_;
    const size_t base = ct0 * C_;
    // stage K tile
    #pragma unroll
    for (int p = 0; p < 16; ++p) {
      int flat = p*256 + tid;
      int row = flat >> 6, c4 = flat & 63;
      *(float4*)&Kl[row][c4*4] = *(const float4*)(kn + base + (size_t)row*C_ + c4*4);
    }
    // stage Z columns, gamma, O preload (+=)
    {
      int s = tid & 63, q = tid >> 6;
      Zl[s][q] = Zb[base + (size_t)s*C_ + i0 + q];
      Ol[s][q] = Oout[base + (size_t)s*C_ + i0 + q];
      if (tid < 64) gaml[tid] = gbuf[ct0 + tid];
    }
    __syncthreads();

    // Pass A: cross output (uses chunk-start S)
    #pragma unroll 2
    for (int t = 0; t < 64; ++t) {
      float4 qv = *(const float4*)(qt + base + (size_t)t*C_ + lane*4);
      float e = red64(dot4(S, qv));
      if (lane == 0) Ol[t][w] += gaml[t] * e;
    }
    // Pass B+C fused: du + state accumulation (S unmodified inside)
    const float gT = gaml[63];
    float4 acc = make_float4(0.f, 0.f, 0.f, 0.f);
    #pragma unroll 2
    for (int s = 0; s < 64; ++s) {
      float4 uv = *(const float4*)(Ubuf + base + (size_t)s*C_ + lane*4);
      float du = red64(dot4(S, uv));
      float coef = gT * du - Zl[s][w];
      float4 kv = *(const float4*)&Kl[s][lane*4];
      acc.x += coef * kv.x;
      acc.y += coef * kv.y;
      acc.z += coef * kv.z;
      acc.w += coef * kv.w;
    }
    S.x = gT*S.x - acc.x;
    S.y = gT*S.y - acc.y;
    S.z = gT*S.z - acc.z;
    S.w = gT*S.w - acc.w;
    __syncthreads();
    // write back O
    {
      int t = tid & 63, q = tid >> 6;
      Oout[base + (size_t)t*C_ + i0 + q] = Ol[t][q];
    }
    __syncthreads();
  }
}

extern "C" void kernel_launch(void* const* d_in, const int* in_sizes, int n_in,
                              void* d_out, int out_size, void* d_ws, size_t ws_size,
                              hipStream_t stream) {
  const float* x  = (const float*)d_in[0];
  const float* Wq = (const float*)d_in[1];  const float* bq = (const float*)d_in[2];
  const float* Wk = (const float*)d_in[3];  const float* bk = (const float*)d_in[4];
  const float* Wv = (const float*)d_in[5];  const float* bv = (const float*)d_in[6];
  const float* Wa = (const float*)d_in[7];  const float* ba = (const float*)d_in[8];
  const float* Wb = (const float*)d_in[9];  const float* bb = (const float*)d_in[10];
  const float* Wo = (const float*)d_in[11]; const float* bo = (const float*)d_in[12];

  float* ws = (float*)d_ws;
  const size_t TC = (size_t)TOK * C_;
  float* qn   = ws;                    // Q -> Qtilde (in place)
  float* kn   = ws + TC;
  float* vO   = ws + 2*TC;             // V -> Z (in place)
  float* Ag   = ws + 3*TC;
  float* Bg   = Ag + TOK;
  float* gbuf = Bg + TOK;
  float* Ubuf = gbuf + TOK;
  float* Gbuf = Ubuf + TC;
  float* QKbuf= Gbuf + (size_t)256*4096;

  GArgs ga;
  ga.W[0] = Wq; ga.W[1] = Wk; ga.W[2] = Wv; ga.W[3] = Wa; ga.W[4] = Wb; ga.W[5] = Wo;
  ga.bias[0] = bq; ga.bias[1] = bk; ga.bias[2] = bv; ga.bias[3] = ba; ga.bias[4] = bb; ga.bias[5] = bo;
  ga.outQ = qn; ga.outK = kn; ga.outV = vO; ga.outA = Ag; ga.outB = Bg;
  ga.outO = (float*)d_out;

  gemm_multi<<<dim3(TOK/64, 5), 256, 0, stream>>>(x, 0, ga);
  gram_kernel<<<dim3(256), 256, 0, stream>>>(kn, qn, Gbuf, QKbuf);
  solve_kernel<<<dim3(256), 256, 0, stream>>>(kn, qn, vO, Ag, Bg, Gbuf, QKbuf,
                                              Ubuf, gbuf, (float*)d_out);
  chunk_scan_kernel<<<dim3(512), 256, 0, stream>>>(kn, qn, Ubuf, vO, gbuf,
                                                   (float*)d_out);
  gemm_multi<<<dim3(TOK/64, 1), 256, 0, stream>>>((float*)d_out, 5, ga);
}

// Round 8
// 1095.765 us; speedup vs baseline: 1.6299x; 1.6299x over previous
//
#include <hip/hip_runtime.h>
#include <math.h>

#define B_ 8
#define N_ 2048
#define C_ 256
#define TOK (B_*N_)
#define T_ 64
#define NCH (N_/T_)   // 32 chunks per batch

struct GArgs {
  const float* W[6];
  const float* bias[6];
  float* outQ; float* outK; float* outV; float* outA; float* outB; float* outO;
};

__device__ __forceinline__ float dot4(const float4& a, const float4& b) {
  return (a.x*b.x + a.y*b.y) + (a.z*b.z + a.w*b.w);
}
__device__ __forceinline__ float rdlane(float x, int idx) {
  return __int_as_float(__builtin_amdgcn_readlane(__float_as_int(x), idx));
}

// ---------------- Tiled f32 GEMM with fused epilogues (unchanged) ----------
__global__ __launch_bounds__(256) void gemm_multi(const float* __restrict__ X,
                                                  int pbase, GArgs ga) {
  const int p = pbase + blockIdx.y;
  const float* __restrict__ Wp = ga.W[p];
  const float* __restrict__ bp = ga.bias[p];
  const int rowBase = blockIdx.x * 64;
  const int tid = threadIdx.x;
  const int tx = tid & 15;
  const int ty = tid >> 4;

  __shared__ float xs[64][33];
  __shared__ float wsm[256][33];

  float acc[4][16];
  #pragma unroll
  for (int r = 0; r < 4; ++r)
    #pragma unroll
    for (int c = 0; c < 16; ++c) acc[r][c] = bp[tx + 16*c];

  for (int k0 = 0; k0 < C_; k0 += 32) {
    #pragma unroll
    for (int pass = 0; pass < 2; ++pass) {
      int flat = (pass*256 + tid) * 4;
      int r = flat >> 5, kk = flat & 31;
      const float4 v = *(const float4*)(X + (size_t)(rowBase + r)*C_ + k0 + kk);
      xs[r][kk] = v.x; xs[r][kk+1] = v.y; xs[r][kk+2] = v.z; xs[r][kk+3] = v.w;
    }
    #pragma unroll
    for (int pass = 0; pass < 8; ++pass) {
      int flat = (pass*256 + tid) * 4;
      int c = flat >> 5, kk = flat & 31;
      const float4 v = *(const float4*)(Wp + (size_t)c*C_ + k0 + kk);
      wsm[c][kk] = v.x; wsm[c][kk+1] = v.y; wsm[c][kk+2] = v.z; wsm[c][kk+3] = v.w;
    }
    __syncthreads();
    #pragma unroll
    for (int kk = 0; kk < 32; ++kk) {
      float xr[4];
      #pragma unroll
      for (int r = 0; r < 4; ++r) xr[r] = xs[ty*4 + r][kk];
      #pragma unroll
      for (int c = 0; c < 16; ++c) {
        float wv = wsm[tx + 16*c][kk];
        #pragma unroll
        for (int r = 0; r < 4; ++r) acc[r][c] += xr[r] * wv;
      }
    }
    __syncthreads();
  }

  if (p <= 2) {
    float part[4] = {0.f, 0.f, 0.f, 0.f};
    #pragma unroll
    for (int r = 0; r < 4; ++r)
      #pragma unroll
      for (int c = 0; c < 16; ++c) {
        float y = acc[r][c];
        float s = y / (1.f + __expf(-y));
        acc[r][c] = s;
        part[r] += s * s;
      }
    float* outp = (p == 0) ? ga.outQ : (p == 1) ? ga.outK : ga.outV;
    if (p == 2) {
      #pragma unroll
      for (int r = 0; r < 4; ++r)
        #pragma unroll
        for (int c = 0; c < 16; ++c)
          outp[(size_t)(rowBase + ty*4 + r)*C_ + tx + 16*c] = acc[r][c];
    } else {
      __syncthreads();
      float* red = &xs[0][0];
      float* rnorm = &wsm[0][0];
      #pragma unroll
      for (int r = 0; r < 4; ++r) red[(ty*4 + r)*17 + tx] = part[r];
      __syncthreads();
      if (tid < 64) {
        float s = 0.f;
        #pragma unroll
        for (int i = 0; i < 16; ++i) s += red[tid*17 + i];
        rnorm[tid] = 1.f / (sqrtf(s) + 1e-6f);
      }
      __syncthreads();
      #pragma unroll
      for (int r = 0; r < 4; ++r) {
        float sc = rnorm[ty*4 + r];
        #pragma unroll
        for (int c = 0; c < 16; ++c)
          outp[(size_t)(rowBase + ty*4 + r)*C_ + tx + 16*c] = acc[r][c] * sc;
      }
    }
  } else if (p <= 4) {
    float part[4] = {0.f, 0.f, 0.f, 0.f};
    #pragma unroll
    for (int r = 0; r < 4; ++r)
      #pragma unroll
      for (int c = 0; c < 16; ++c) {
        float y = acc[r][c];
        part[r] += 1.f / (1.f + __expf(-y));
      }
    __syncthreads();
    float* red = &xs[0][0];
    #pragma unroll
    for (int r = 0; r < 4; ++r) red[(ty*4 + r)*17 + tx] = part[r];
    __syncthreads();
    if (tid < 64) {
      float s = 0.f;
      #pragma unroll
      for (int i = 0; i < 16; ++i) s += red[tid*17 + i];
      ((p == 3) ? ga.outA : ga.outB)[rowBase + tid] = s * (1.f / 256.f);
    }
  } else {
    #pragma unroll
    for (int r = 0; r < 4; ++r)
      #pragma unroll
      for (int c = 0; c < 16; ++c)
        ga.outO[(size_t)(rowBase + ty*4 + r)*C_ + tx + 16*c] = acc[r][c];
  }
}

// ---------------- fused gram + WY solves + intra output --------------------
// grid 256 = (b = bid&7, c = bid>>3); 256 threads (thread = column j).
// Computes per chunk: G = KK^T, QK = QK^T (LDS panels); gamma; U solve;
// Qtilde (in place over qn); scale -> Ghat/Omega; Y solve; Z (in place over
// vO); O_intra -> Oout. u_/y_ arrays are registers: ALL indices static
// (outer solve loops fully unrolled; masked Gl rows make partial f4 groups
// safe since Gl[s][r>=s]=0 and unwritten u_ elements are 0).
__global__ __launch_bounds__(256) void chunk_prep(const float* __restrict__ kn,
                                                  float* __restrict__ qn,
                                                  float* __restrict__ vO,
                                                  const float* __restrict__ Ag,
                                                  const float* __restrict__ Bg,
                                                  float* __restrict__ Ubuf,
                                                  float* __restrict__ gbuf,
                                                  float* __restrict__ Oout) {
  __shared__ float Gl[64][68];
  __shared__ float Wl[64][68];
  __shared__ float Kp[64][68];
  __shared__ float Qp[64][68];
  __shared__ float gam[64], al[64], bl[64];
  const int bid = blockIdx.x;
  const int b = bid & 7, c = bid >> 3;
  const size_t ct0 = (size_t)b*N_ + (size_t)c*T_;
  const size_t base = ct0 * C_;
  const int tid = threadIdx.x;
  const int lane = tid & 63;   // row index in gram
  const int sg = tid >> 6;     // column group

  if (tid < 64) { al[tid] = Ag[ct0 + tid]; bl[tid] = Bg[ct0 + tid]; }

  // ---- gram over 4 k-panels ----
  float accG[16], accQ[16];
  #pragma unroll
  for (int m = 0; m < 16; ++m) { accG[m] = 0.f; accQ[m] = 0.f; }
  for (int p = 0; p < 4; ++p) {
    __syncthreads();
    #pragma unroll
    for (int i = 0; i < 4; ++i) {
      int idx = i*256 + tid;            // 1024 float4 tiles
      int row = idx >> 4, c4 = idx & 15;
      *(float4*)&Kp[row][c4*4] = *(const float4*)(kn + base + (size_t)row*C_ + p*64 + c4*4);
      *(float4*)&Qp[row][c4*4] = *(const float4*)(qn + base + (size_t)row*C_ + p*64 + c4*4);
    }
    __syncthreads();
    #pragma unroll 4
    for (int j4 = 0; j4 < 16; ++j4) {
      float4 kt = *(const float4*)&Kp[lane][j4*4];
      float4 qt = *(const float4*)&Qp[lane][j4*4];
      #pragma unroll
      for (int m = 0; m < 16; ++m) {
        float4 ks = *(const float4*)&Kp[sg*16 + m][j4*4];  // wave-uniform bcast
        accG[m] += dot4(kt, ks);
        accQ[m] += dot4(qt, ks);
      }
    }
  }
  __syncthreads();
  #pragma unroll
  for (int m = 0; m < 16; ++m) {
    int col = sg*16 + m;
    Gl[lane][col] = (col <  lane) ? accG[m] : 0.f;  // strict lower
    Wl[lane][col] = (col <= lane) ? accQ[m] : 0.f;  // lower incl diag
  }
  __syncthreads();
  if (tid == 0) {
    float g = 1.f;
    for (int s = 0; s < 64; ++s) { g *= al[s]; gam[s] = g; }
  }
  __syncthreads();
  if (tid < 64) gbuf[ct0 + tid] = gam[tid];

  const int j = tid;  // column 0..255

  // ---- U solve (registers, static indices) ----
  float u_[64];
  #pragma unroll
  for (int i = 0; i < 64; ++i) u_[i] = 0.f;
  #pragma unroll 64
  for (int s = 0; s < 64; ++s) {
    float acc = kn[base + (size_t)s*C_ + j];
    #pragma unroll
    for (int r4 = 0; r4 <= (s >> 2); ++r4) {
      float4 g = *(const float4*)&Gl[s][r4*4];
      acc -= g.x*u_[r4*4] + g.y*u_[r4*4+1] + g.z*u_[r4*4+2] + g.w*u_[r4*4+3];
    }
    u_[s] = bl[s] * acc;
    Ubuf[base + (size_t)s*C_ + j] = u_[s];
  }
  // ---- Qtilde in place ----
  for (int t = 0; t < 64; ++t) {
    float acc = qn[base + (size_t)t*C_ + j];
    #pragma unroll
    for (int s4 = 0; s4 < 16; ++s4) {
      float4 w = *(const float4*)&Wl[t][s4*4];
      acc -= w.x*u_[s4*4] + w.y*u_[s4*4+1] + w.z*u_[s4*4+2] + w.w*u_[s4*4+3];
    }
    qn[base + (size_t)t*C_ + j] = acc;
  }
  __syncthreads();
  // ---- scale: Gl -> Ghat, Wl -> Omega ----
  #pragma unroll
  for (int p2 = 0; p2 < 16; ++p2) {
    int idx = p2*256 + tid; int s = idx >> 6, r = idx & 63;
    float rs = gam[s] / gam[r];
    Gl[s][r] *= rs;
    Wl[s][r] *= rs;
  }
  __syncthreads();
  const float gT = gam[63];
  // ---- Y solve ----
  float y_[64];
  #pragma unroll
  for (int i = 0; i < 64; ++i) y_[i] = 0.f;
  #pragma unroll 64
  for (int s = 0; s < 64; ++s) {
    float acc = vO[base + (size_t)s*C_ + j];
    #pragma unroll
    for (int r4 = 0; r4 <= (s >> 2); ++r4) {
      float4 g = *(const float4*)&Gl[s][r4*4];
      acc -= g.x*y_[r4*4] + g.y*y_[r4*4+1] + g.z*y_[r4*4+2] + g.w*y_[r4*4+3];
    }
    y_[s] = bl[s] * acc;
    vO[base + (size_t)s*C_ + j] = (gT / gam[s]) * y_[s];   // Z in place
  }
  // ---- O_intra = Omega * y ----
  for (int t = 0; t < 64; ++t) {
    float acc = 0.f;
    #pragma unroll
    for (int s4 = 0; s4 < 16; ++s4) {
      float4 w = *(const float4*)&Wl[t][s4*4];
      acc += w.x*y_[s4*4] + w.y*y_[s4*4+1] + w.z*y_[s4*4+2] + w.w*y_[s4*4+3];
    }
    Oout[base + (size_t)t*C_ + j] = acc;
  }
}

// ---------------- serial chunk scan (readlane form) -----------------------
// grid 1024 = (b = bid&7, rowpair = bid>>3); ONE 64-lane wave per WG.
// WG owns 2 rows of S: lane l holds S[r][4l..4l+3] (float4 S0,S1).
// Per chunk: PassA o_cross (q~ row per lane=t, S via readlane, uniform idx);
// PassB du (U rows, lane=s); coef = gT*du - Z; PassC S update (lane=k-block,
// coef via readlane, K rows coalesced). No LDS, no barriers, no reduces.
__global__ __launch_bounds__(64) void chunk_scan(const float* __restrict__ kn,
                                                 const float* __restrict__ qt,
                                                 const float* __restrict__ Ubuf,
                                                 const float* __restrict__ Zb,
                                                 const float* __restrict__ gbuf,
                                                 float* __restrict__ Oout) {
  const int bid = blockIdx.x;
  const int b = bid & 7;
  const int i0 = (bid >> 3) * 2;
  const int lane = threadIdx.x;

  float4 S0 = make_float4(0.f,0.f,0.f,0.f);
  float4 S1 = make_float4(0.f,0.f,0.f,0.f);

  for (int ch = 0; ch < NCH; ++ch) {
    const size_t ct0 = (size_t)b*N_ + (size_t)ch*T_;
    const size_t base = ct0 * C_;
    const float gv = gbuf[ct0 + lane];
    const float gT = rdlane(gv, 63);

    // Pass A: o_cross[t=lane][i0..i0+1] = gam_t * (S . q~_t)
    float oa = 0.f, ob = 0.f;
    const float* qrow = qt + base + (size_t)lane*C_;
    #pragma unroll 8
    for (int k4 = 0; k4 < 64; ++k4) {
      float4 qv = *(const float4*)(qrow + k4*4);
      oa += rdlane(S0.x,k4)*qv.x + rdlane(S0.y,k4)*qv.y
          + rdlane(S0.z,k4)*qv.z + rdlane(S0.w,k4)*qv.w;
      ob += rdlane(S1.x,k4)*qv.x + rdlane(S1.y,k4)*qv.y
          + rdlane(S1.z,k4)*qv.z + rdlane(S1.w,k4)*qv.w;
    }
    float* orow = Oout + base + (size_t)lane*C_ + i0;
    float o0 = orow[0], o1 = orow[1];
    orow[0] = o0 + gv*oa;
    orow[1] = o1 + gv*ob;

    // Pass B: du[s=lane][i0..i0+1] = S . u_s ; coef = gT*du - Z
    float da = 0.f, db = 0.f;
    const float* urow = Ubuf + base + (size_t)lane*C_;
    #pragma unroll 8
    for (int k4 = 0; k4 < 64; ++k4) {
      float4 uv = *(const float4*)(urow + k4*4);
      da += rdlane(S0.x,k4)*uv.x + rdlane(S0.y,k4)*uv.y
          + rdlane(S0.z,k4)*uv.z + rdlane(S0.w,k4)*uv.w;
      db += rdlane(S1.x,k4)*uv.x + rdlane(S1.y,k4)*uv.y
          + rdlane(S1.z,k4)*uv.z + rdlane(S1.w,k4)*uv.w;
    }
    const float* zrow = Zb + base + (size_t)lane*C_ + i0;
    float cfa = gT*da - zrow[0];
    float cfb = gT*db - zrow[1];

    // Pass C: S' = gT*S - sum_s coef[s] * k_s   (lane = k-block, coalesced K)
    float4 A0 = make_float4(0.f,0.f,0.f,0.f);
    float4 A1 = make_float4(0.f,0.f,0.f,0.f);
    #pragma unroll 8
    for (int s = 0; s < 64; ++s) {
      float4 kv = *(const float4*)(kn + base + (size_t)s*C_ + lane*4);
      float ca = rdlane(cfa, s), cb = rdlane(cfb, s);
      A0.x += ca*kv.x; A0.y += ca*kv.y; A0.z += ca*kv.z; A0.w += ca*kv.w;
      A1.x += cb*kv.x; A1.y += cb*kv.y; A1.z += cb*kv.z; A1.w += cb*kv.w;
    }
    S0.x = gT*S0.x - A0.x; S0.y = gT*S0.y - A0.y;
    S0.z = gT*S0.z - A0.z; S0.w = gT*S0.w - A0.w;
    S1.x = gT*S1.x - A1.x; S1.y = gT*S1.y - A1.y;
    S1.z = gT*S1.z - A1.z; S1.w = gT*S1.w - A1.w;
  }
}

extern "C" void kernel_launch(void* const* d_in, const int* in_sizes, int n_in,
                              void* d_out, int out_size, void* d_ws, size_t ws_size,
                              hipStream_t stream) {
  const float* x  = (const float*)d_in[0];
  const float* Wq = (const float*)d_in[1];  const float* bq = (const float*)d_in[2];
  const float* Wk = (const float*)d_in[3];  const float* bk = (const float*)d_in[4];
  const float* Wv = (const float*)d_in[5];  const float* bv = (const float*)d_in[6];
  const float* Wa = (const float*)d_in[7];  const float* ba = (const float*)d_in[8];
  const float* Wb = (const float*)d_in[9];  const float* bb = (const float*)d_in[10];
  const float* Wo = (const float*)d_in[11]; const float* bo = (const float*)d_in[12];

  float* ws = (float*)d_ws;
  const size_t TC = (size_t)TOK * C_;
  float* qn   = ws;                    // Q -> Qtilde (in place)
  float* kn   = ws + TC;
  float* vO   = ws + 2*TC;             // V -> Z (in place)
  float* Ag   = ws + 3*TC;
  float* Bg   = Ag + TOK;
  float* gbuf = Bg + TOK;
  float* Ubuf = gbuf + TOK;

  GArgs ga;
  ga.W[0] = Wq; ga.W[1] = Wk; ga.W[2] = Wv; ga.W[3] = Wa; ga.W[4] = Wb; ga.W[5] = Wo;
  ga.bias[0] = bq; ga.bias[1] = bk; ga.bias[2] = bv; ga.bias[3] = ba; ga.bias[4] = bb; ga.bias[5] = bo;
  ga.outQ = qn; ga.outK = kn; ga.outV = vO; ga.outA = Ag; ga.outB = Bg;
  ga.outO = (float*)d_out;

  gemm_multi<<<dim3(TOK/64, 5), 256, 0, stream>>>(x, 0, ga);
  chunk_prep<<<dim3(256), 256, 0, stream>>>(kn, qn, vO, Ag, Bg, Ubuf, gbuf,
                                            (float*)d_out);
  chunk_scan<<<dim3(1024), 64, 0, stream>>>(kn, qn, Ubuf, vO, gbuf,
                                            (float*)d_out);
  gemm_multi<<<dim3(TOK/64, 1), 256, 0, stream>>>((float*)d_out, 5, ga);
}

// Round 9
// 986.093 us; speedup vs baseline: 1.8112x; 1.1112x over previous
//
#include <hip/hip_runtime.h>
#include <math.h>

#define B_ 8
#define N_ 2048
#define C_ 256
#define TOK (B_*N_)
#define T_ 64
#define NCH (N_/T_)   // 32 chunks per batch

struct GArgs {
  const float* W[6];
  const float* bias[6];
  float* outQ; float* outK; float* outV; float* outA; float* outB; float* outO;
};

__device__ __forceinline__ float dot4(const float4& a, const float4& b) {
  return (a.x*b.x + a.y*b.y) + (a.z*b.z + a.w*b.w);
}
__device__ __forceinline__ float rdlane(float x, int idx) {
  return __int_as_float(__builtin_amdgcn_readlane(__float_as_int(x), idx));
}

// ---------------- Tiled f32 GEMM with fused epilogues (unchanged) ----------
__global__ __launch_bounds__(256) void gemm_multi(const float* __restrict__ X,
                                                  int pbase, GArgs ga) {
  const int p = pbase + blockIdx.y;
  const float* __restrict__ Wp = ga.W[p];
  const float* __restrict__ bp = ga.bias[p];
  const int rowBase = blockIdx.x * 64;
  const int tid = threadIdx.x;
  const int tx = tid & 15;
  const int ty = tid >> 4;

  __shared__ float xs[64][33];
  __shared__ float wsm[256][33];

  float acc[4][16];
  #pragma unroll
  for (int r = 0; r < 4; ++r)
    #pragma unroll
    for (int c = 0; c < 16; ++c) acc[r][c] = bp[tx + 16*c];

  for (int k0 = 0; k0 < C_; k0 += 32) {
    #pragma unroll
    for (int pass = 0; pass < 2; ++pass) {
      int flat = (pass*256 + tid) * 4;
      int r = flat >> 5, kk = flat & 31;
      const float4 v = *(const float4*)(X + (size_t)(rowBase + r)*C_ + k0 + kk);
      xs[r][kk] = v.x; xs[r][kk+1] = v.y; xs[r][kk+2] = v.z; xs[r][kk+3] = v.w;
    }
    #pragma unroll
    for (int pass = 0; pass < 8; ++pass) {
      int flat = (pass*256 + tid) * 4;
      int c = flat >> 5, kk = flat & 31;
      const float4 v = *(const float4*)(Wp + (size_t)c*C_ + k0 + kk);
      wsm[c][kk] = v.x; wsm[c][kk+1] = v.y; wsm[c][kk+2] = v.z; wsm[c][kk+3] = v.w;
    }
    __syncthreads();
    #pragma unroll
    for (int kk = 0; kk < 32; ++kk) {
      float xr[4];
      #pragma unroll
      for (int r = 0; r < 4; ++r) xr[r] = xs[ty*4 + r][kk];
      #pragma unroll
      for (int c = 0; c < 16; ++c) {
        float wv = wsm[tx + 16*c][kk];
        #pragma unroll
        for (int r = 0; r < 4; ++r) acc[r][c] += xr[r] * wv;
      }
    }
    __syncthreads();
  }

  if (p <= 2) {
    float part[4] = {0.f, 0.f, 0.f, 0.f};
    #pragma unroll
    for (int r = 0; r < 4; ++r)
      #pragma unroll
      for (int c = 0; c < 16; ++c) {
        float y = acc[r][c];
        float s = y / (1.f + __expf(-y));
        acc[r][c] = s;
        part[r] += s * s;
      }
    float* outp = (p == 0) ? ga.outQ : (p == 1) ? ga.outK : ga.outV;
    if (p == 2) {
      #pragma unroll
      for (int r = 0; r < 4; ++r)
        #pragma unroll
        for (int c = 0; c < 16; ++c)
          outp[(size_t)(rowBase + ty*4 + r)*C_ + tx + 16*c] = acc[r][c];
    } else {
      __syncthreads();
      float* red = &xs[0][0];
      float* rnorm = &wsm[0][0];
      #pragma unroll
      for (int r = 0; r < 4; ++r) red[(ty*4 + r)*17 + tx] = part[r];
      __syncthreads();
      if (tid < 64) {
        float s = 0.f;
        #pragma unroll
        for (int i = 0; i < 16; ++i) s += red[tid*17 + i];
        rnorm[tid] = 1.f / (sqrtf(s) + 1e-6f);
      }
      __syncthreads();
      #pragma unroll
      for (int r = 0; r < 4; ++r) {
        float sc = rnorm[ty*4 + r];
        #pragma unroll
        for (int c = 0; c < 16; ++c)
          outp[(size_t)(rowBase + ty*4 + r)*C_ + tx + 16*c] = acc[r][c] * sc;
      }
    }
  } else if (p <= 4) {
    float part[4] = {0.f, 0.f, 0.f, 0.f};
    #pragma unroll
    for (int r = 0; r < 4; ++r)
      #pragma unroll
      for (int c = 0; c < 16; ++c) {
        float y = acc[r][c];
        part[r] += 1.f / (1.f + __expf(-y));
      }
    __syncthreads();
    float* red = &xs[0][0];
    #pragma unroll
    for (int r = 0; r < 4; ++r) red[(ty*4 + r)*17 + tx] = part[r];
    __syncthreads();
    if (tid < 64) {
      float s = 0.f;
      #pragma unroll
      for (int i = 0; i < 16; ++i) s += red[tid*17 + i];
      ((p == 3) ? ga.outA : ga.outB)[rowBase + tid] = s * (1.f / 256.f);
    }
  } else {
    #pragma unroll
    for (int r = 0; r < 4; ++r)
      #pragma unroll
      for (int c = 0; c < 16; ++c)
        ga.outO[(size_t)(rowBase + ty*4 + r)*C_ + tx + 16*c] = acc[r][c];
  }
}

// ---------------- fused gram + WY solves + intra output --------------------
// grid 256 = (b = bid&7, c = bid>>3); 256 threads (thread = column j).
// Per chunk: G=KK^T, QK=QK^T (LDS); gamma; U solve; Qtilde; scale; Y solve;
// O_intra. U, Qtilde, Z are written CHUNK-TRANSPOSED ([j][s] layout: elem
// (s,j) at chunkbase + j*64 + s) so the scan's column reads are coalesced.
// Qtilde^T overwrites qn, Z^T overwrites vO -- reg-buffered, then a
// __syncthreads separates all chunk reads from the transposed stores.
__global__ __launch_bounds__(256) void chunk_prep(const float* __restrict__ kn,
                                                  float* __restrict__ qn,
                                                  float* __restrict__ vO,
                                                  const float* __restrict__ Ag,
                                                  const float* __restrict__ Bg,
                                                  float* __restrict__ Ubuf,
                                                  float* __restrict__ gbuf,
                                                  float* __restrict__ Oout) {
  __shared__ float Gl[64][68];
  __shared__ float Wl[64][68];
  __shared__ float Kp[64][68];
  __shared__ float Qp[64][68];
  __shared__ float gam[64], al[64], bl[64];
  const int bid = blockIdx.x;
  const int b = bid & 7, c = bid >> 3;
  const size_t ct0 = (size_t)b*N_ + (size_t)c*T_;
  const size_t base = ct0 * C_;
  const int tid = threadIdx.x;
  const int lane = tid & 63;   // row index in gram
  const int sg = tid >> 6;     // column group

  if (tid < 64) { al[tid] = Ag[ct0 + tid]; bl[tid] = Bg[ct0 + tid]; }

  // ---- gram over 4 k-panels ----
  float accG[16], accQ[16];
  #pragma unroll
  for (int m = 0; m < 16; ++m) { accG[m] = 0.f; accQ[m] = 0.f; }
  for (int p = 0; p < 4; ++p) {
    __syncthreads();
    #pragma unroll
    for (int i = 0; i < 4; ++i) {
      int idx = i*256 + tid;            // 1024 float4 tiles
      int row = idx >> 4, c4 = idx & 15;
      *(float4*)&Kp[row][c4*4] = *(const float4*)(kn + base + (size_t)row*C_ + p*64 + c4*4);
      *(float4*)&Qp[row][c4*4] = *(const float4*)(qn + base + (size_t)row*C_ + p*64 + c4*4);
    }
    __syncthreads();
    #pragma unroll 4
    for (int j4 = 0; j4 < 16; ++j4) {
      float4 kt = *(const float4*)&Kp[lane][j4*4];
      float4 qt = *(const float4*)&Qp[lane][j4*4];
      #pragma unroll
      for (int m = 0; m < 16; ++m) {
        float4 ks = *(const float4*)&Kp[sg*16 + m][j4*4];  // wave-uniform bcast
        accG[m] += dot4(kt, ks);
        accQ[m] += dot4(qt, ks);
      }
    }
  }
  __syncthreads();
  #pragma unroll
  for (int m = 0; m < 16; ++m) {
    int col = sg*16 + m;
    Gl[lane][col] = (col <  lane) ? accG[m] : 0.f;  // strict lower
    Wl[lane][col] = (col <= lane) ? accQ[m] : 0.f;  // lower incl diag
  }
  __syncthreads();
  if (tid == 0) {
    float g = 1.f;
    for (int s = 0; s < 64; ++s) { g *= al[s]; gam[s] = g; }
  }
  __syncthreads();
  if (tid < 64) gbuf[ct0 + tid] = gam[tid];

  const int j = tid;  // column 0..255

  // ---- U solve (registers, static indices) ----
  float u_[64];
  #pragma unroll
  for (int i = 0; i < 64; ++i) u_[i] = 0.f;
  #pragma unroll 64
  for (int s = 0; s < 64; ++s) {
    float acc = kn[base + (size_t)s*C_ + j];
    #pragma unroll
    for (int r4 = 0; r4 <= (s >> 2); ++r4) {
      float4 g = *(const float4*)&Gl[s][r4*4];
      acc -= g.x*u_[r4*4] + g.y*u_[r4*4+1] + g.z*u_[r4*4+2] + g.w*u_[r4*4+3];
    }
    u_[s] = bl[s] * acc;
  }
  // store U^T (chunk-transposed, batched float4)
  #pragma unroll
  for (int s4 = 0; s4 < 16; ++s4)
    *(float4*)&Ubuf[base + (size_t)j*64 + s4*4] =
      make_float4(u_[s4*4], u_[s4*4+1], u_[s4*4+2], u_[s4*4+3]);

  // ---- Qtilde into registers ----
  float qt_[64];
  #pragma unroll 64
  for (int t = 0; t < 64; ++t) {
    float acc = qn[base + (size_t)t*C_ + j];
    #pragma unroll
    for (int s4 = 0; s4 < 16; ++s4) {
      float4 w = *(const float4*)&Wl[t][s4*4];
      acc -= w.x*u_[s4*4] + w.y*u_[s4*4+1] + w.z*u_[s4*4+2] + w.w*u_[s4*4+3];
    }
    qt_[t] = acc;
  }
  __syncthreads();   // all qn chunk reads done
  #pragma unroll
  for (int t4 = 0; t4 < 16; ++t4)
    *(float4*)&qn[base + (size_t)j*64 + t4*4] =
      make_float4(qt_[t4*4], qt_[t4*4+1], qt_[t4*4+2], qt_[t4*4+3]);  // Q~^T

  // ---- scale: Gl -> Ghat, Wl -> Omega ----
  __syncthreads();
  #pragma unroll
  for (int p2 = 0; p2 < 16; ++p2) {
    int idx = p2*256 + tid; int s = idx >> 6, r = idx & 63;
    float rs = gam[s] / gam[r];
    Gl[s][r] *= rs;
    Wl[s][r] *= rs;
  }
  __syncthreads();
  const float gT = gam[63];
  // ---- Y solve ----
  float y_[64];
  #pragma unroll
  for (int i = 0; i < 64; ++i) y_[i] = 0.f;
  #pragma unroll 64
  for (int s = 0; s < 64; ++s) {
    float acc = vO[base + (size_t)s*C_ + j];
    #pragma unroll
    for (int r4 = 0; r4 <= (s >> 2); ++r4) {
      float4 g = *(const float4*)&Gl[s][r4*4];
      acc -= g.x*y_[r4*4] + g.y*y_[r4*4+1] + g.z*y_[r4*4+2] + g.w*y_[r4*4+3];
    }
    y_[s] = bl[s] * acc;
  }
  __syncthreads();   // all vO chunk reads done
  #pragma unroll
  for (int s4 = 0; s4 < 16; ++s4) {
    float z0 = (gT / gam[s4*4+0]) * y_[s4*4+0];
    float z1 = (gT / gam[s4*4+1]) * y_[s4*4+1];
    float z2 = (gT / gam[s4*4+2]) * y_[s4*4+2];
    float z3 = (gT / gam[s4*4+3]) * y_[s4*4+3];
    *(float4*)&vO[base + (size_t)j*64 + s4*4] = make_float4(z0, z1, z2, z3);  // Z^T
  }
  // ---- O_intra = Omega * y ----
  for (int t = 0; t < 64; ++t) {
    float acc = 0.f;
    #pragma unroll
    for (int s4 = 0; s4 < 16; ++s4) {
      float4 w = *(const float4*)&Wl[t][s4*4];
      acc += w.x*y_[s4*4] + w.y*y_[s4*4+1] + w.z*y_[s4*4+2] + w.w*y_[s4*4+3];
    }
    Oout[base + (size_t)t*C_ + j] = acc;
  }
}

// ---------------- serial chunk scan (coalesced transposed reads) ----------
// grid 256 = (b = bid&7, wgrp = bid>>3); 256 threads = 4 waves; each wave
// owns 2 rows of S (i0 = wgrp*8 + wave*2). All tile reads are column reads
// of chunk-transposed buffers -> 256B coalesced per wave-load. S elements
// broadcast via v_readlane (static component, uniform index). Co-resident
// waves stream identical tiles -> L1 reuse. No LDS, no barriers.
__global__ __launch_bounds__(256) void chunk_scan(const float* __restrict__ kn,
                                                  const float* __restrict__ qtT,
                                                  const float* __restrict__ utT,
                                                  const float* __restrict__ ztT,
                                                  const float* __restrict__ gbuf,
                                                  float* __restrict__ Oout) {
  const int bid = blockIdx.x;
  const int b = bid & 7;
  const int wgrp = bid >> 3;
  const int tid = threadIdx.x;
  const int wave = tid >> 6, lane = tid & 63;
  const int i0 = wgrp*8 + wave*2;

  float4 S0 = make_float4(0.f,0.f,0.f,0.f);
  float4 S1 = make_float4(0.f,0.f,0.f,0.f);

  for (int ch = 0; ch < NCH; ++ch) {
    const size_t ct0 = (size_t)b*N_ + (size_t)ch*T_;
    const size_t base = ct0 * C_;
    const float gv = gbuf[ct0 + lane];
    const float gT = rdlane(gv, 63);
    const float* qb = qtT + base;
    const float* ub = utT + base;

    // Pass A: o_cross[t] = gam_t * (S . q~_t), lane = t
    float oa = 0.f, ob = 0.f;
    #pragma unroll 8
    for (int j4 = 0; j4 < 64; ++j4) {
      const float* cp = qb + j4*256 + lane;
      float c0 = cp[0], c1 = cp[64], c2 = cp[128], c3 = cp[192];
      oa += rdlane(S0.x,j4)*c0 + rdlane(S0.y,j4)*c1
          + rdlane(S0.z,j4)*c2 + rdlane(S0.w,j4)*c3;
      ob += rdlane(S1.x,j4)*c0 + rdlane(S1.y,j4)*c1
          + rdlane(S1.z,j4)*c2 + rdlane(S1.w,j4)*c3;
    }
    float* orow = Oout + base + (size_t)lane*C_ + i0;
    orow[0] += gv*oa;
    orow[1] += gv*ob;

    // Pass B: du[s] = S . u_s, lane = s
    float da = 0.f, db = 0.f;
    #pragma unroll 8
    for (int j4 = 0; j4 < 64; ++j4) {
      const float* cp = ub + j4*256 + lane;
      float c0 = cp[0], c1 = cp[64], c2 = cp[128], c3 = cp[192];
      da += rdlane(S0.x,j4)*c0 + rdlane(S0.y,j4)*c1
          + rdlane(S0.z,j4)*c2 + rdlane(S0.w,j4)*c3;
      db += rdlane(S1.x,j4)*c0 + rdlane(S1.y,j4)*c1
          + rdlane(S1.z,j4)*c2 + rdlane(S1.w,j4)*c3;
    }
    float z0 = ztT[base + (size_t)i0*64 + lane];
    float z1 = ztT[base + (size_t)(i0+1)*64 + lane];
    float cfa = gT*da - z0;
    float cfb = gT*db - z1;

    // Pass C: S' = gT*S - sum_s coef[s]*k_s  (lane = k-col-block, coalesced)
    float4 A0 = make_float4(0.f,0.f,0.f,0.f);
    float4 A1 = make_float4(0.f,0.f,0.f,0.f);
    #pragma unroll 8
    for (int s = 0; s < 64; ++s) {
      float4 kv = *(const float4*)(kn + base + (size_t)s*C_ + lane*4);
      float ca = rdlane(cfa, s), cb = rdlane(cfb, s);
      A0.x += ca*kv.x; A0.y += ca*kv.y; A0.z += ca*kv.z; A0.w += ca*kv.w;
      A1.x += cb*kv.x; A1.y += cb*kv.y; A1.z += cb*kv.z; A1.w += cb*kv.w;
    }
    S0.x = gT*S0.x - A0.x; S0.y = gT*S0.y - A0.y;
    S0.z = gT*S0.z - A0.z; S0.w = gT*S0.w - A0.w;
    S1.x = gT*S1.x - A1.x; S1.y = gT*S1.y - A1.y;
    S1.z = gT*S1.z - A1.z; S1.w = gT*S1.w - A1.w;
  }
}

extern "C" void kernel_launch(void* const* d_in, const int* in_sizes, int n_in,
                              void* d_out, int out_size, void* d_ws, size_t ws_size,
                              hipStream_t stream) {
  const float* x  = (const float*)d_in[0];
  const float* Wq = (const float*)d_in[1];  const float* bq = (const float*)d_in[2];
  const float* Wk = (const float*)d_in[3];  const float* bk = (const float*)d_in[4];
  const float* Wv = (const float*)d_in[5];  const float* bv = (const float*)d_in[6];
  const float* Wa = (const float*)d_in[7];  const float* ba = (const float*)d_in[8];
  const float* Wb = (const float*)d_in[9];  const float* bb = (const float*)d_in[10];
  const float* Wo = (const float*)d_in[11]; const float* bo = (const float*)d_in[12];

  float* ws = (float*)d_ws;
  const size_t TC = (size_t)TOK * C_;
  float* qn   = ws;                    // Q -> Qtilde^T (chunk-transposed)
  float* kn   = ws + TC;
  float* vO   = ws + 2*TC;             // V -> Z^T (chunk-transposed)
  float* Ag   = ws + 3*TC;
  float* Bg   = Ag + TOK;
  float* gbuf = Bg + TOK;
  float* Ubuf = gbuf + TOK;            // U^T (chunk-transposed)

  GArgs ga;
  ga.W[0] = Wq; ga.W[1] = Wk; ga.W[2] = Wv; ga.W[3] = Wa; ga.W[4] = Wb; ga.W[5] = Wo;
  ga.bias[0] = bq; ga.bias[1] = bk; ga.bias[2] = bv; ga.bias[3] = ba; ga.bias[4] = bb; ga.bias[5] = bo;
  ga.outQ = qn; ga.outK = kn; ga.outV = vO; ga.outA = Ag; ga.outB = Bg;
  ga.outO = (float*)d_out;

  gemm_multi<<<dim3(TOK/64, 5), 256, 0, stream>>>(x, 0, ga);
  chunk_prep<<<dim3(256), 256, 0, stream>>>(kn, qn, vO, Ag, Bg, Ubuf, gbuf,
                                            (float*)d_out);
  chunk_scan<<<dim3(256), 256, 0, stream>>>(kn, qn, Ubuf, vO, gbuf,
                                            (float*)d_out);
  gemm_multi<<<dim3(TOK/64, 1), 256, 0, stream>>>((float*)d_out, 5, ga);
}